// Round 6
// baseline (465.383 us; speedup 1.0000x reference)
//
#include <hip/hip_runtime.h>
#include <hip/hip_bf16.h>
#include <cstdint>

#define BB 4
#define TT 2048
#define CC 1024
#define HH 16
#define HS 64
#define MM (BB*TT)   // 8192

// scores computed in exp2 domain: fold 8 * log2(e) into Q once (QKV epilogue)
#define QSCALE 11.5415603629f

typedef _Float16 f16;
typedef _Float16 f16x8 __attribute__((ext_vector_type(8)));
typedef _Float16 f16x4 __attribute__((ext_vector_type(4)));
typedef float f32x4 __attribute__((ext_vector_type(4)));

#define MFMA16(a,b,c) __builtin_amdgcn_mfma_f32_16x16x32_f16(a,b,c,0,0,0)

__device__ __forceinline__ void g2lds16(void* lds, const void* g) {
  __builtin_amdgcn_global_load_lds(
      (const __attribute__((address_space(1))) void*)g,
      (__attribute__((address_space(3))) void*)lds, 16, 0, 0);
}

// ---------------- pre-pass: f32 -> f16 convert ----------------
__global__ __launch_bounds__(256) void cvt_kernel(const float* __restrict__ in,
                                                  f16* __restrict__ out, int n4) {
  int i = blockIdx.x * blockDim.x + threadIdx.x;
  if (i < n4) {
    float4 v = ((const float4*)in)[i];
    f16x4 o;
    o[0] = (f16)v.x; o[1] = (f16)v.y; o[2] = (f16)v.z; o[3] = (f16)v.w;
    ((f16x4*)out)[i] = o;
  }
}

// ---------------- pre-pass: transpose + convert: in[K][N] f32 -> out[N][K] f16
__global__ __launch_bounds__(256) void transpose_cvt(const float* __restrict__ in,
                                                     f16* __restrict__ out,
                                                     int K, int N) {
  __shared__ float tile[32][33];
  int n0 = blockIdx.x * 32, k0 = blockIdx.y * 32;
  int tx = threadIdx.x, ty = threadIdx.y;
  #pragma unroll
  for (int i = 0; i < 32; i += 8)
    tile[ty + i][tx] = in[(size_t)(k0 + ty + i) * N + n0 + tx];
  __syncthreads();
  #pragma unroll
  for (int i = 0; i < 32; i += 8)
    out[(size_t)(n0 + ty + i) * K + k0 + tx] = (f16)tile[tx][ty + i];
}

// ---------------- GEMM: C[M][N] = A[M][1024] * Bt[N][1024]^T ----------------
template<int EPI>
__global__ __launch_bounds__(256) void gemm_bt(const f16* __restrict__ A,
                                               const f16* __restrict__ Bt,
                                               f16* __restrict__ qT,
                                               f16* __restrict__ kT,
                                               f16* __restrict__ vT,
                                               const float* __restrict__ bias,
                                               float* __restrict__ outF) {
  const int K = 1024;
  __shared__ f16 As[128 * 64];
  __shared__ f16 Bs[128 * 64];
  const int t = threadIdx.x;
  const int l = t & 63, w = t >> 6;
  const int lr = l & 15, lh = l >> 4;
  const int row0 = blockIdx.y * 128, col0 = blockIdx.x * 128;
  const int wr = (w >> 1) * 64, wc = (w & 1) * 64;

  f32x4 acc[4][4] = {};

  for (int kt = 0; kt < K; kt += 64) {
    #pragma unroll
    for (int issue = 0; issue < 4; ++issue) {
      int r  = issue * 32 + w * 8 + (l >> 3);
      int cb = (l & 7) * 8;
      g2lds16(&As[r * 64 + cb], &A [(size_t)(row0 + r) * K + kt + cb]);
      g2lds16(&Bs[r * 64 + cb], &Bt[(size_t)(col0 + r) * K + kt + cb]);
    }
    __syncthreads();
    #pragma unroll
    for (int kk = 0; kk < 64; kk += 32) {
      f16x8 af[4], bfr[4];
      #pragma unroll
      for (int m = 0; m < 4; ++m)
        af[m]  = *(const f16x8*)&As[(wr + m * 16 + lr) * 64 + kk + lh * 8];
      #pragma unroll
      for (int n = 0; n < 4; ++n)
        bfr[n] = *(const f16x8*)&Bs[(wc + n * 16 + lr) * 64 + kk + lh * 8];
      #pragma unroll
      for (int m = 0; m < 4; ++m)
        #pragma unroll
        for (int n = 0; n < 4; ++n)
          acc[m][n] = MFMA16(af[m], bfr[n], acc[m][n]);
    }
    __syncthreads();
  }

  #pragma unroll
  for (int m = 0; m < 4; ++m) {
    #pragma unroll
    for (int n = 0; n < 4; ++n) {
      #pragma unroll
      for (int j = 0; j < 4; ++j) {
        float val = acc[m][n][j];
        int gr = row0 + wr + m * 16 + lh * 4 + j;   // M index
        int gc = col0 + wc + n * 16 + lr;           // N index
        if (EPI == 0) {
          int which = gc >> 10;          // 0=q 1=k 2=v
          int c = gc & 1023;
          int h = c >> 6, d = c & 63;
          int b = gr >> 11, tt = gr & 2047;
          size_t bh = (size_t)(b * HH + h);
          if (which == 0)      qT[(bh * TT + tt) * HS + d] = (f16)(val * QSCALE);
          else if (which == 1) kT[(bh * TT + tt) * HS + d] = (f16)val;
          else                 vT[(bh * HS + d) * TT + tt] = (f16)val;
        } else {
          outF[(size_t)gr * CC + gc] = val + bias[gc];
        }
      }
    }
  }
}

// ---------------- flash attention, k-split flash-decode ----------------
// grid (64 bh, 16 qp). block 512 = 8 waves = 4 row-groups x 2 k-halves.
// Each wave: 16 q rows of tile qp then tile 31-qp, half the k-range each;
// merge (m,l,o) across the k-half pair via LDS. Defer-max THR=12 (exact).
// Q is pre-scaled by 8*log2(e) -> softmax via exp2.
template<bool MASKED>
__device__ __forceinline__ void attn_step(
    int kb, int q, int lr, int lh,
    const f16* __restrict__ Kb, const f16* __restrict__ Vb,
    f16* Prow, int swz, f16x8 qf0, f16x8 qf1,
    float& m, float& lsum, f32x4 (&o)[4]) {
  const f16* kbase = Kb + ((size_t)kb + lr) * HS + lh * 8;
  f16x8 kf0 = *(const f16x8*)(kbase);
  f16x8 kf1 = *(const f16x8*)(kbase + 32);
  f16x8 kf2 = *(const f16x8*)(kbase + 16 * HS);
  f16x8 kf3 = *(const f16x8*)(kbase + 16 * HS + 32);
  f32x4 s0 = {}, s1 = {};
  s0 = MFMA16(kf0, qf0, s0);
  s0 = MFMA16(kf1, qf1, s0);
  s1 = MFMA16(kf2, qf0, s1);
  s1 = MFMA16(kf3, qf1, s1);
  float p[8];
  if (MASKED) {
    const int k0 = kb + lh * 4;
    #pragma unroll
    for (int r = 0; r < 4; ++r) {
      p[r]     = (k0 + r      <= q) ? s0[r] : -INFINITY;
      p[4 + r] = (k0 + 16 + r <= q) ? s1[r] : -INFINITY;
    }
  } else {
    #pragma unroll
    for (int r = 0; r < 4; ++r) { p[r] = s0[r]; p[4 + r] = s1[r]; }
  }
  float mx = p[0];
  #pragma unroll
  for (int i = 1; i < 8; ++i) mx = fmaxf(mx, p[i]);
  mx = fmaxf(mx, __shfl_xor(mx, 16));
  mx = fmaxf(mx, __shfl_xor(mx, 32));
  if (__any(mx > m + 12.0f)) {           // rescale path (rare after warm-up)
    float mn = fmaxf(m, mx);
    float corr = exp2f(m - mn);
    m = mn;
    float ps = 0.f;
    #pragma unroll
    for (int i = 0; i < 8; ++i) { p[i] = exp2f(p[i] - mn); ps += p[i]; }
    ps += __shfl_xor(ps, 16);
    ps += __shfl_xor(ps, 32);
    lsum = lsum * corr + ps;
    float c4[4];
    #pragma unroll
    for (int r = 0; r < 4; ++r) c4[r] = __shfl(corr, lh * 4 + r);
    #pragma unroll
    for (int dg = 0; dg < 4; ++dg)
      #pragma unroll
      for (int r = 0; r < 4; ++r) o[dg][r] *= c4[r];
  } else {                               // deferred max: no rescale
    float ps = 0.f;
    #pragma unroll
    for (int i = 0; i < 8; ++i) { p[i] = exp2f(p[i] - m); ps += p[i]; }
    ps += __shfl_xor(ps, 16);
    ps += __shfl_xor(ps, 32);
    lsum += ps;
  }
  f16x4 pw0, pw1;
  #pragma unroll
  for (int r = 0; r < 4; ++r) { pw0[r] = (f16)p[r]; pw1[r] = (f16)p[4 + r]; }
  *(f16x4*)&Prow[(lh * 4) ^ swz]        = pw0;
  *(f16x4*)&Prow[(lh * 4 + 16) ^ swz]   = pw1;
  f16x8 pf = *(const f16x8*)&Prow[(lh * 8) ^ swz];
  #pragma unroll
  for (int dg = 0; dg < 4; ++dg) {
    f16x8 vf = *(const f16x8*)&Vb[(size_t)(dg * 16 + lr) * TT + kb + lh * 8];
    o[dg] = MFMA16(pf, vf, o[dg]);
  }
}

__global__ __launch_bounds__(512, 8) void attn_kernel(const f16* __restrict__ qT,
                                                      const f16* __restrict__ kT,
                                                      const f16* __restrict__ vT,
                                                      f16* __restrict__ aout) {
  const int bh = blockIdx.x;     // x-fastest: 16 blocks of one bh on XCD bh%8
  const int qp = blockIdx.y;     // 0..15
  const int t = threadIdx.x, l = t & 63, w = t >> 6;
  const int rg = w & 3;          // row-group (16 q rows each)
  const int kh = w >> 2;         // k-half: 0 = lower, 1 = upper(+diagonal)
  const int lr = l & 15, lh = l >> 4;
  const f16* __restrict__ Qb = qT + (size_t)bh * TT * HS;
  const f16* __restrict__ Kb = kT + (size_t)bh * TT * HS;
  const f16* __restrict__ Vb = vT + (size_t)bh * HS * TT;
  const int b = bh >> 4, h = bh & 15;

  __attribute__((aligned(16))) __shared__ f16   P_lds[8][16][32];   // 8KB wave-private
  __attribute__((aligned(16))) __shared__ float O_lds[4][64][16];   // 16KB upper->lower
  __shared__ float ML_lds[4][16][2];                                // 512B

  const int swz = (lr & 3) << 3;     // f16-unit XOR swizzle (function of row lr)
  f16* Prow = &P_lds[w][lr][0];

  #pragma unroll
  for (int half = 0; half < 2; ++half) {
    const int tile = half ? (31 - qp) : qp;
    const int q0 = tile * 64 + rg * 16;
    const int q = q0 + lr;
    const int kend  = (q0 & ~31) + 32;        // exclusive end of k tiles
    const int kfull = q0 & ~31;               // the single masked (diagonal) tile
    const int khalf = (kend >> 1) & ~31;      // split point
    const int kbeg      = kh ? khalf : 0;
    const int kmain_end = kh ? kfull : khalf; // full (unmasked) region

    f16x8 qf0 = *(const f16x8*)&Qb[(size_t)q * HS + lh * 8];
    f16x8 qf1 = *(const f16x8*)&Qb[(size_t)q * HS + 32 + lh * 8];

    float m = -INFINITY, lsum = 0.f;
    f32x4 o[4] = {};

    for (int kb = kbeg; kb < kmain_end; kb += 32)
      attn_step<false>(kb, q, lr, lh, Kb, Vb, Prow, swz, qf0, qf1, m, lsum, o);
    if (kh)
      attn_step<true>(kfull, q, lr, lh, Kb, Vb, Prow, swz, qf0, qf1, m, lsum, o);

    // ---- merge the two k-halves ----
    if (kh) {
      #pragma unroll
      for (int dg = 0; dg < 4; ++dg)
        *(f32x4*)&O_lds[rg][l][(dg * 4) ^ ((l & 3) << 2)] = o[dg];
      if (lh == 0) { ML_lds[rg][lr][0] = m; ML_lds[rg][lr][1] = lsum; }
    }
    __syncthreads();
    if (!kh) {
      float mB = ML_lds[rg][lr][0];
      float lB = ML_lds[rg][lr][1];
      float mS = fmaxf(m, mB);                 // mB always finite
      float cA = exp2f(m - mS);
      float cB = exp2f(mB - mS);
      float li = 1.0f / (lsum * cA + lB * cB);
      float sA = cA * li, sB = cB * li;
      float sA4[4], sB4[4];
      #pragma unroll
      for (int r = 0; r < 4; ++r) {
        sA4[r] = __shfl(sA, lh * 4 + r);
        sB4[r] = __shfl(sB, lh * 4 + r);
      }
      #pragma unroll
      for (int dg = 0; dg < 4; ++dg) {
        f32x4 ob = *(const f32x4*)&O_lds[rg][l][(dg * 4) ^ ((l & 3) << 2)];
        #pragma unroll
        for (int r = 0; r < 4; ++r) {
          int qq = q0 + lh * 4 + r;
          float val = o[dg][r] * sA4[r] + ob[r] * sB4[r];
          aout[((size_t)(b * TT + qq)) * CC + h * HS + dg * 16 + lr] = (f16)val;
        }
      }
    }
    __syncthreads();   // protect O_lds/ML_lds reuse by next tile
  }
}

// ---------------- launch ----------------
extern "C" void kernel_launch(void* const* d_in, const int* in_sizes, int n_in,
                              void* d_out, int out_size, void* d_ws, size_t ws_size,
                              hipStream_t stream) {
  const float* x      = (const float*)d_in[0];
  const float* w_kqv  = (const float*)d_in[1];
  const float* w_proj = (const float*)d_in[2];
  const float* b_proj = (const float*)d_in[3];
  float* out = (float*)d_out;

  char* ws = (char*)d_ws;
  f16* xb    = (f16*)(ws);                       // 16,777,216 B
  f16* wkqvT = (f16*)(ws + 16777216);            //  6,291,456
  f16* wpT   = (f16*)(ws + 23068672);            //  2,097,152
  f16* qT    = (f16*)(ws + 25165824);            // 16,777,216
  f16* kT    = (f16*)(ws + 41943040);            // 16,777,216
  f16* vT    = (f16*)(ws + 58720256);            // 16,777,216
  f16* aout  = (f16*)(ws + 75497472);            // 16,777,216  -> ~92.3 MB

  cvt_kernel<<<8192, 256, 0, stream>>>(x, xb, (MM * CC) / 4);
  transpose_cvt<<<dim3(3 * CC / 32, CC / 32), dim3(32, 8), 0, stream>>>(w_kqv, wkqvT, CC, 3 * CC);
  transpose_cvt<<<dim3(CC / 32, CC / 32), dim3(32, 8), 0, stream>>>(w_proj, wpT, CC, CC);

  gemm_bt<0><<<dim3(3 * CC / 128, MM / 128), 256, 0, stream>>>(xb, wkqvT, qT, kT, vT, nullptr, nullptr);

  attn_kernel<<<dim3(BB * HH, 16), 512, 0, stream>>>(qT, kT, vT, aout);

  gemm_bt<1><<<dim3(CC / 128, MM / 128), 256, 0, stream>>>(aout, wpT, nullptr, nullptr, nullptr, b_proj, out);
}

// Round 7
// 380.819 us; speedup vs baseline: 1.2221x; 1.2221x over previous
//
#include <hip/hip_runtime.h>
#include <hip/hip_bf16.h>
#include <cstdint>

#define BB 4
#define TT 2048
#define CC 1024
#define HH 16
#define HS 64
#define MM (BB*TT)   // 8192

// scores computed in exp2 domain: fold 8 * log2(e) into Q once (QKV epilogue)
#define QSCALE 11.5415603629f

typedef _Float16 f16;
typedef _Float16 f16x8 __attribute__((ext_vector_type(8)));
typedef _Float16 f16x4 __attribute__((ext_vector_type(4)));
typedef float f32x4 __attribute__((ext_vector_type(4)));

#define MFMA16(a,b,c) __builtin_amdgcn_mfma_f32_16x16x32_f16(a,b,c,0,0,0)

__device__ __forceinline__ void g2lds16(void* lds, const void* g) {
  __builtin_amdgcn_global_load_lds(
      (const __attribute__((address_space(1))) void*)g,
      (__attribute__((address_space(3))) void*)lds, 16, 0, 0);
}

// ---------------- pre-pass: f32 -> f16 convert ----------------
__global__ __launch_bounds__(256) void cvt_kernel(const float* __restrict__ in,
                                                  f16* __restrict__ out, int n4) {
  int i = blockIdx.x * blockDim.x + threadIdx.x;
  if (i < n4) {
    float4 v = ((const float4*)in)[i];
    f16x4 o;
    o[0] = (f16)v.x; o[1] = (f16)v.y; o[2] = (f16)v.z; o[3] = (f16)v.w;
    ((f16x4*)out)[i] = o;
  }
}

// ---------------- pre-pass: transpose + convert: in[K][N] f32 -> out[N][K] f16
__global__ __launch_bounds__(256) void transpose_cvt(const float* __restrict__ in,
                                                     f16* __restrict__ out,
                                                     int K, int N) {
  __shared__ float tile[32][33];
  int n0 = blockIdx.x * 32, k0 = blockIdx.y * 32;
  int tx = threadIdx.x, ty = threadIdx.y;
  #pragma unroll
  for (int i = 0; i < 32; i += 8)
    tile[ty + i][tx] = in[(size_t)(k0 + ty + i) * N + n0 + tx];
  __syncthreads();
  #pragma unroll
  for (int i = 0; i < 32; i += 8)
    out[(size_t)(n0 + ty + i) * K + k0 + tx] = (f16)tile[tx][ty + i];
}

// ---------------- GEMM: C[M][N] = A[M][1024] * Bt[N][1024]^T ----------------
template<int EPI>
__global__ __launch_bounds__(256) void gemm_bt(const f16* __restrict__ A,
                                               const f16* __restrict__ Bt,
                                               f16* __restrict__ qT,
                                               f16* __restrict__ kT,
                                               f16* __restrict__ vT,
                                               const float* __restrict__ bias,
                                               float* __restrict__ outF) {
  const int K = 1024;
  __shared__ f16 As[128 * 64];
  __shared__ f16 Bs[128 * 64];
  const int t = threadIdx.x;
  const int l = t & 63, w = t >> 6;
  const int lr = l & 15, lh = l >> 4;
  const int row0 = blockIdx.y * 128, col0 = blockIdx.x * 128;
  const int wr = (w >> 1) * 64, wc = (w & 1) * 64;

  f32x4 acc[4][4] = {};

  for (int kt = 0; kt < K; kt += 64) {
    #pragma unroll
    for (int issue = 0; issue < 4; ++issue) {
      int r  = issue * 32 + w * 8 + (l >> 3);
      int cb = (l & 7) * 8;
      g2lds16(&As[r * 64 + cb], &A [(size_t)(row0 + r) * K + kt + cb]);
      g2lds16(&Bs[r * 64 + cb], &Bt[(size_t)(col0 + r) * K + kt + cb]);
    }
    __syncthreads();
    #pragma unroll
    for (int kk = 0; kk < 64; kk += 32) {
      f16x8 af[4], bfr[4];
      #pragma unroll
      for (int m = 0; m < 4; ++m)
        af[m]  = *(const f16x8*)&As[(wr + m * 16 + lr) * 64 + kk + lh * 8];
      #pragma unroll
      for (int n = 0; n < 4; ++n)
        bfr[n] = *(const f16x8*)&Bs[(wc + n * 16 + lr) * 64 + kk + lh * 8];
      #pragma unroll
      for (int m = 0; m < 4; ++m)
        #pragma unroll
        for (int n = 0; n < 4; ++n)
          acc[m][n] = MFMA16(af[m], bfr[n], acc[m][n]);
    }
    __syncthreads();
  }

  #pragma unroll
  for (int m = 0; m < 4; ++m) {
    #pragma unroll
    for (int n = 0; n < 4; ++n) {
      #pragma unroll
      for (int j = 0; j < 4; ++j) {
        float val = acc[m][n][j];
        int gr = row0 + wr + m * 16 + lh * 4 + j;   // M index
        int gc = col0 + wc + n * 16 + lr;           // N index
        if (EPI == 0) {
          int which = gc >> 10;          // 0=q 1=k 2=v
          int c = gc & 1023;
          int h = c >> 6, d = c & 63;
          int b = gr >> 11, tt = gr & 2047;
          size_t bh = (size_t)(b * HH + h);
          if (which == 0)      qT[(bh * TT + tt) * HS + d] = (f16)(val * QSCALE);
          else if (which == 1) kT[(bh * TT + tt) * HS + d] = (f16)val;
          else                 vT[(bh * HS + d) * TT + tt] = (f16)val;
        } else {
          outF[(size_t)gr * CC + gc] = val + bias[gc];
        }
      }
    }
  }
}

// ---------------- flash attention, k-split flash-decode ----------------
// grid (64 bh, 16 qp). block 512 = 8 waves = 4 row-groups x 2 k-halves.
// launch_bounds (512,4): VGPR cap 128 -> NO SPILLS (round-6 used (512,8) ->
// 64-VGPR cap -> accumulator spills -> 628MB scratch fetch; this is the fix).
// Defer-max THR=12; lsum kept as per-lane partials, reduced once at the end.
template<bool MASKED>
__device__ __forceinline__ void attn_step(
    int kb, int q, int lr, int lh,
    const f16* __restrict__ Kb, const f16* __restrict__ Vb,
    f16* Prow, int swz, f16x8 qf0, f16x8 qf1,
    float& m, float& lsum, f32x4 (&o)[4]) {
  const f16* kbase = Kb + ((size_t)kb + lr) * HS + lh * 8;
  f16x8 kf0 = *(const f16x8*)(kbase);
  f16x8 kf1 = *(const f16x8*)(kbase + 32);
  f16x8 kf2 = *(const f16x8*)(kbase + 16 * HS);
  f16x8 kf3 = *(const f16x8*)(kbase + 16 * HS + 32);
  f32x4 s0 = {}, s1 = {};
  s0 = MFMA16(kf0, qf0, s0);
  s0 = MFMA16(kf1, qf1, s0);
  s1 = MFMA16(kf2, qf0, s1);
  s1 = MFMA16(kf3, qf1, s1);
  float p[8];
  if (MASKED) {
    const int k0 = kb + lh * 4;
    #pragma unroll
    for (int r = 0; r < 4; ++r) {
      p[r]     = (k0 + r      <= q) ? s0[r] : -INFINITY;
      p[4 + r] = (k0 + 16 + r <= q) ? s1[r] : -INFINITY;
    }
  } else {
    #pragma unroll
    for (int r = 0; r < 4; ++r) { p[r] = s0[r]; p[4 + r] = s1[r]; }
  }
  float mx = p[0];
  #pragma unroll
  for (int i = 1; i < 8; ++i) mx = fmaxf(mx, p[i]);
  mx = fmaxf(mx, __shfl_xor(mx, 16));
  mx = fmaxf(mx, __shfl_xor(mx, 32));
  if (__any(mx > m + 12.0f)) {           // rescale path (rare)
    float mn = fmaxf(m, mx);
    float corr = exp2f(m - mn);          // uniform across the q-row's 4 lanes
    m = mn;
    float ps = 0.f;
    #pragma unroll
    for (int i = 0; i < 8; ++i) { p[i] = exp2f(p[i] - mn); ps += p[i]; }
    lsum = lsum * corr + ps;             // per-lane partial; reduced at end
    float c4[4];
    #pragma unroll
    for (int r = 0; r < 4; ++r) c4[r] = __shfl(corr, lh * 4 + r);
    #pragma unroll
    for (int dg = 0; dg < 4; ++dg)
      #pragma unroll
      for (int r = 0; r < 4; ++r) o[dg][r] *= c4[r];
  } else {                               // deferred max: no rescale, no shfl
    float ps = 0.f;
    #pragma unroll
    for (int i = 0; i < 8; ++i) { p[i] = exp2f(p[i] - m); ps += p[i]; }
    lsum += ps;
  }
  f16x4 pw0, pw1;
  #pragma unroll
  for (int r = 0; r < 4; ++r) { pw0[r] = (f16)p[r]; pw1[r] = (f16)p[4 + r]; }
  *(f16x4*)&Prow[(lh * 4) ^ swz]        = pw0;
  *(f16x4*)&Prow[(lh * 4 + 16) ^ swz]   = pw1;
  f16x8 pf = *(const f16x8*)&Prow[(lh * 8) ^ swz];
  #pragma unroll
  for (int dg = 0; dg < 4; ++dg) {
    f16x8 vf = *(const f16x8*)&Vb[(size_t)(dg * 16 + lr) * TT + kb + lh * 8];
    o[dg] = MFMA16(pf, vf, o[dg]);
  }
}

__global__ __launch_bounds__(512, 4) void attn_kernel(const f16* __restrict__ qT,
                                                      const f16* __restrict__ kT,
                                                      const f16* __restrict__ vT,
                                                      f16* __restrict__ aout) {
  const int bh = blockIdx.x;     // x-fastest: 16 blocks of one bh on XCD bh%8
  const int qp = blockIdx.y;     // 0..15
  const int t = threadIdx.x, l = t & 63, w = t >> 6;
  const int rg = w & 3;          // row-group (16 q rows each)
  const int kh = w >> 2;         // k-half: 0 = lower, 1 = upper(+diagonal)
  const int lr = l & 15, lh = l >> 4;
  const f16* __restrict__ Qb = qT + (size_t)bh * TT * HS;
  const f16* __restrict__ Kb = kT + (size_t)bh * TT * HS;
  const f16* __restrict__ Vb = vT + (size_t)bh * HS * TT;
  const int b = bh >> 4, h = bh & 15;

  // P rows padded to 40 f16 (80 B = 20 banks, 16B-aligned): write/read bank
  // aliasing drops to the free 2-way (rows lr and lr+8 share a pattern).
  __attribute__((aligned(16))) __shared__ f16   P_lds[8][16][40];   // 10 KB
  __attribute__((aligned(16))) __shared__ float O_lds[4][64][16];   // 16 KB
  __shared__ float ML_lds[4][16][2];                                // 512 B

  const int swz = (lr & 3) << 3;     // f16-unit XOR swizzle (multiple of 8)
  f16* Prow = &P_lds[w][lr][0];

  #pragma unroll
  for (int half = 0; half < 2; ++half) {
    const int tile = half ? (31 - qp) : qp;
    const int q0 = tile * 64 + rg * 16;
    const int q = q0 + lr;
    const int kend  = (q0 & ~31) + 32;        // exclusive end of k tiles
    const int kfull = q0 & ~31;               // the single masked (diagonal) tile
    const int khalf = (kend >> 1) & ~31;      // split point
    const int kbeg      = kh ? khalf : 0;
    const int kmain_end = kh ? kfull : khalf; // full (unmasked) region

    f16x8 qf0 = *(const f16x8*)&Qb[(size_t)q * HS + lh * 8];
    f16x8 qf1 = *(const f16x8*)&Qb[(size_t)q * HS + 32 + lh * 8];

    float m = -INFINITY, lsum = 0.f;
    f32x4 o[4] = {};

    for (int kb = kbeg; kb < kmain_end; kb += 32)
      attn_step<false>(kb, q, lr, lh, Kb, Vb, Prow, swz, qf0, qf1, m, lsum, o);
    if (kh)
      attn_step<true>(kfull, q, lr, lh, Kb, Vb, Prow, swz, qf0, qf1, m, lsum, o);

    // reduce the per-lane lsum partials across the q-row's 4 lanes
    lsum += __shfl_xor(lsum, 16);
    lsum += __shfl_xor(lsum, 32);

    // ---- merge the two k-halves ----
    if (kh) {
      #pragma unroll
      for (int dg = 0; dg < 4; ++dg)
        *(f32x4*)&O_lds[rg][l][(dg * 4) ^ ((l & 3) << 2)] = o[dg];
      if (lh == 0) { ML_lds[rg][lr][0] = m; ML_lds[rg][lr][1] = lsum; }
    }
    __syncthreads();
    if (!kh) {
      float mB = ML_lds[rg][lr][0];
      float lB = ML_lds[rg][lr][1];
      float mS = fmaxf(m, mB);                 // mB always finite
      float cA = exp2f(m - mS);
      float cB = exp2f(mB - mS);
      float li = 1.0f / (lsum * cA + lB * cB);
      float sA = cA * li, sB = cB * li;
      float sA4[4], sB4[4];
      #pragma unroll
      for (int r = 0; r < 4; ++r) {
        sA4[r] = __shfl(sA, lh * 4 + r);
        sB4[r] = __shfl(sB, lh * 4 + r);
      }
      #pragma unroll
      for (int dg = 0; dg < 4; ++dg) {
        f32x4 ob = *(const f32x4*)&O_lds[rg][l][(dg * 4) ^ ((l & 3) << 2)];
        #pragma unroll
        for (int r = 0; r < 4; ++r) {
          int qq = q0 + lh * 4 + r;
          float val = o[dg][r] * sA4[r] + ob[r] * sB4[r];
          aout[((size_t)(b * TT + qq)) * CC + h * HS + dg * 16 + lr] = (f16)val;
        }
      }
    }
    __syncthreads();   // protect O_lds/ML_lds reuse by next tile
  }
}

// ---------------- launch ----------------
extern "C" void kernel_launch(void* const* d_in, const int* in_sizes, int n_in,
                              void* d_out, int out_size, void* d_ws, size_t ws_size,
                              hipStream_t stream) {
  const float* x      = (const float*)d_in[0];
  const float* w_kqv  = (const float*)d_in[1];
  const float* w_proj = (const float*)d_in[2];
  const float* b_proj = (const float*)d_in[3];
  float* out = (float*)d_out;

  char* ws = (char*)d_ws;
  f16* xb    = (f16*)(ws);                       // 16,777,216 B
  f16* wkqvT = (f16*)(ws + 16777216);            //  6,291,456
  f16* wpT   = (f16*)(ws + 23068672);            //  2,097,152
  f16* qT    = (f16*)(ws + 25165824);            // 16,777,216
  f16* kT    = (f16*)(ws + 41943040);            // 16,777,216
  f16* vT    = (f16*)(ws + 58720256);            // 16,777,216
  f16* aout  = (f16*)(ws + 75497472);            // 16,777,216  -> ~92.3 MB

  cvt_kernel<<<8192, 256, 0, stream>>>(x, xb, (MM * CC) / 4);
  transpose_cvt<<<dim3(3 * CC / 32, CC / 32), dim3(32, 8), 0, stream>>>(w_kqv, wkqvT, CC, 3 * CC);
  transpose_cvt<<<dim3(CC / 32, CC / 32), dim3(32, 8), 0, stream>>>(w_proj, wpT, CC, CC);

  gemm_bt<0><<<dim3(3 * CC / 128, MM / 128), 256, 0, stream>>>(xb, wkqvT, qT, kT, vT, nullptr, nullptr);

  attn_kernel<<<dim3(BB * HH, 16), 512, 0, stream>>>(qT, kT, vT, aout);

  gemm_bt<1><<<dim3(CC / 128, MM / 128), 256, 0, stream>>>(aout, wpT, nullptr, nullptr, nullptr, b_proj, out);
}

// Round 9
// 271.269 us; speedup vs baseline: 1.7156x; 1.4038x over previous
//
#include <hip/hip_runtime.h>
#include <hip/hip_bf16.h>
#include <cstdint>

#define BB 4
#define TT 2048
#define CC 1024
#define HH 16
#define HS 64
#define MM (BB*TT)   // 8192

// scores computed in exp2 domain: fold 8 * log2(e) into Q once (QKV epilogue)
#define QSCALE 11.5415603629f

typedef _Float16 f16;
typedef _Float16 f16x8 __attribute__((ext_vector_type(8)));
typedef _Float16 f16x4 __attribute__((ext_vector_type(4)));
typedef float f32x4 __attribute__((ext_vector_type(4)));
typedef float f32x16 __attribute__((ext_vector_type(16)));

#define MFMA16(a,b,c) __builtin_amdgcn_mfma_f32_16x16x32_f16(a,b,c,0,0,0)
#define MFMA32(a,b,c) __builtin_amdgcn_mfma_f32_32x32x16_f16(a,b,c,0,0,0)

__device__ __forceinline__ void g2lds16(void* lds, const void* g) {
  __builtin_amdgcn_global_load_lds(
      (const __attribute__((address_space(1))) void*)g,
      (__attribute__((address_space(3))) void*)lds, 16, 0, 0);
}

__device__ __forceinline__ int pk2(float a, float b) {
  auto r = __builtin_amdgcn_cvt_pkrtz(a, b);   // __fp16 ext_vector(2)
  return __builtin_bit_cast(int, r);
}

union U8 { int4 i; f16x8 h; };

// ---------------- pre-pass: f32 -> f16 convert ----------------
__global__ __launch_bounds__(256) void cvt_kernel(const float* __restrict__ in,
                                                  f16* __restrict__ out, int n4) {
  int i = blockIdx.x * blockDim.x + threadIdx.x;
  if (i < n4) {
    float4 v = ((const float4*)in)[i];
    f16x4 o;
    o[0] = (f16)v.x; o[1] = (f16)v.y; o[2] = (f16)v.z; o[3] = (f16)v.w;
    ((f16x4*)out)[i] = o;
  }
}

// ---------------- pre-pass: transpose + convert: in[K][N] f32 -> out[N][K] f16
__global__ __launch_bounds__(256) void transpose_cvt(const float* __restrict__ in,
                                                     f16* __restrict__ out,
                                                     int K, int N) {
  __shared__ float tile[32][33];
  int n0 = blockIdx.x * 32, k0 = blockIdx.y * 32;
  int tx = threadIdx.x, ty = threadIdx.y;
  #pragma unroll
  for (int i = 0; i < 32; i += 8)
    tile[ty + i][tx] = in[(size_t)(k0 + ty + i) * N + n0 + tx];
  __syncthreads();
  #pragma unroll
  for (int i = 0; i < 32; i += 8)
    out[(size_t)(n0 + ty + i) * K + k0 + tx] = (f16)tile[tx][ty + i];
}

// ---------------- GEMM: C[M][N] = A[M][1024] * Bt[N][1024]^T ----------------
template<int EPI>
__global__ __launch_bounds__(256) void gemm_bt(const f16* __restrict__ A,
                                               const f16* __restrict__ Bt,
                                               f16* __restrict__ qT,
                                               f16* __restrict__ kT,
                                               f16* __restrict__ vT,
                                               const float* __restrict__ bias,
                                               float* __restrict__ outF) {
  const int K = 1024;
  __shared__ f16 As[128 * 64];
  __shared__ f16 Bs[128 * 64];
  const int t = threadIdx.x;
  const int l = t & 63, w = t >> 6;
  const int lr = l & 15, lh = l >> 4;
  const int row0 = blockIdx.y * 128, col0 = blockIdx.x * 128;
  const int wr = (w >> 1) * 64, wc = (w & 1) * 64;

  f32x4 acc[4][4] = {};

  for (int kt = 0; kt < K; kt += 64) {
    #pragma unroll
    for (int issue = 0; issue < 4; ++issue) {
      int r  = issue * 32 + w * 8 + (l >> 3);
      int cb = (l & 7) * 8;
      g2lds16(&As[r * 64 + cb], &A [(size_t)(row0 + r) * K + kt + cb]);
      g2lds16(&Bs[r * 64 + cb], &Bt[(size_t)(col0 + r) * K + kt + cb]);
    }
    __syncthreads();
    #pragma unroll
    for (int kk = 0; kk < 64; kk += 32) {
      f16x8 af[4], bfr[4];
      #pragma unroll
      for (int m = 0; m < 4; ++m)
        af[m]  = *(const f16x8*)&As[(wr + m * 16 + lr) * 64 + kk + lh * 8];
      #pragma unroll
      for (int n = 0; n < 4; ++n)
        bfr[n] = *(const f16x8*)&Bs[(wc + n * 16 + lr) * 64 + kk + lh * 8];
      #pragma unroll
      for (int m = 0; m < 4; ++m)
        #pragma unroll
        for (int n = 0; n < 4; ++n)
          acc[m][n] = MFMA16(af[m], bfr[n], acc[m][n]);
    }
    __syncthreads();
  }

  #pragma unroll
  for (int m = 0; m < 4; ++m) {
    #pragma unroll
    for (int n = 0; n < 4; ++n) {
      #pragma unroll
      for (int j = 0; j < 4; ++j) {
        float val = acc[m][n][j];
        int gr = row0 + wr + m * 16 + lh * 4 + j;   // M index
        int gc = col0 + wc + n * 16 + lr;           // N index
        if (EPI == 0) {
          int which = gc >> 10;          // 0=q 1=k 2=v
          int c = gc & 1023;
          int h = c >> 6, d = c & 63;
          int b = gr >> 11, tt = gr & 2047;
          size_t bh = (size_t)(b * HH + h);
          if (which == 0)      qT[(bh * TT + tt) * HS + d] = (f16)(val * QSCALE);
          else if (which == 1) kT[(bh * TT + tt) * HS + d] = (f16)val;
          else                 vT[(bh * HS + d) * TT + tt] = (f16)val;
        } else {
          outF[(size_t)gr * CC + gc] = val + bias[gc];
        }
      }
    }
  }
}

// ---------------- flash attention v3: 32x32 MFMA, in-register softmax -------
// S^T = mfma32(K, Q): lane holds 16 scores for q = l&31 (k-rows per C-layout).
// O^T = mfma32(V^T, P^T): output col ALSO q = l&31 -> softmax stats, rescale,
// and epilogue are fully per-lane (no broadcasts, no LDS P round-trip).
// P^T reaches the B-frag via 8 cvt_pkrtz + 8 shfl_xor(32) (half-swap).
template<bool MASKED>
__device__ __forceinline__ void step32(
    int kb, int qa, int l31, int hi,
    const f16* __restrict__ Kb, const f16* __restrict__ Vb,
    const f16x8 (&qf)[4],
    float& m, float& lsum, f32x16& oA, f32x16& oB) {
  // QK^T (4 MFMAs over d=64)
  f32x16 s = {};
  const f16* kp = Kb + ((size_t)kb + l31) * HS + hi * 8;
  #pragma unroll
  for (int j = 0; j < 4; ++j) {
    f16x8 kf = *(const f16x8*)(kp + 16 * j);
    s = MFMA32(kf, qf[j], s);
  }
  float p[16];
  #pragma unroll
  for (int r = 0; r < 16; ++r) {
    if (MASKED) {
      int k = kb + (r & 3) + 8 * (r >> 2) + 4 * hi;
      p[r] = (k <= qa) ? s[r] : -INFINITY;
    } else p[r] = s[r];
  }
  float mx = p[0];
  #pragma unroll
  for (int r = 1; r < 16; ++r) mx = fmaxf(mx, p[r]);
  mx = fmaxf(mx, __shfl_xor(mx, 32));
  float mn = fmaxf(m, mx);
  float corr = __builtin_amdgcn_exp2f(m - mn);
  m = mn;
  float ps = 0.f;
  #pragma unroll
  for (int r = 0; r < 16; ++r) {
    p[r] = __builtin_amdgcn_exp2f(p[r] - mn);
    ps += p[r];
  }
  lsum = lsum * corr + ps;
  #pragma unroll
  for (int r = 0; r < 16; ++r) { oA[r] *= corr; oB[r] *= corr; }
  // P -> f16 pairs; exchange lane-halves to build B-frags (k=kb..+15, +16..+31)
  int pk[8], xk[8];
  #pragma unroll
  for (int j = 0; j < 8; ++j) pk[j] = pk2(p[2 * j], p[2 * j + 1]);
  #pragma unroll
  for (int j = 0; j < 8; ++j) xk[j] = __shfl_xor(pk[j], 32);
  U8 b0, b1;
  b0.i = (int4){ hi ? xk[2] : pk[0], hi ? xk[3] : pk[1],
                 hi ? pk[2] : xk[0], hi ? pk[3] : xk[1] };
  b1.i = (int4){ hi ? xk[6] : pk[4], hi ? xk[7] : pk[5],
                 hi ? pk[6] : xk[4], hi ? pk[7] : xk[5] };
  // PV (4 MFMAs: 2 k-slices x 2 d-blocks)
  const f16* vp = Vb + (size_t)l31 * TT + kb + hi * 8;
  f16x8 v00 = *(const f16x8*)(vp);
  f16x8 v01 = *(const f16x8*)(vp + 16);
  const f16* vp1 = vp + 32 * TT;
  f16x8 v10 = *(const f16x8*)(vp1);
  f16x8 v11 = *(const f16x8*)(vp1 + 16);
  oA = MFMA32(v00, b0.h, oA);
  oA = MFMA32(v01, b1.h, oA);
  oB = MFMA32(v10, b0.h, oB);
  oB = MFMA32(v11, b1.h, oB);
}

// grid (64 bh, 16 pg). block 256 = 4 waves = 2 pairs x 2 k-halves.
// Wave owns a 32-row q-tile; pairs (p, 63-p) balance the causal triangle.
__global__ __launch_bounds__(256, 3) void attn_kernel(const f16* __restrict__ qT,
                                                      const f16* __restrict__ kT,
                                                      const f16* __restrict__ vT,
                                                      f16* __restrict__ aout) {
  const int bh = blockIdx.x;   // x-fastest: all 16 blocks of a bh on XCD bh%8
  const int pg = blockIdx.y;
  const int t = threadIdx.x, l = t & 63, w = t >> 6;
  const int pl = w & 1;        // pair-local slot
  const int kh = w >> 1;       // k-half: 1 = upper (owns diagonal)
  const int l31 = l & 31, hi = l >> 5;
  const int pair = pg * 2 + pl;
  const f16* __restrict__ Qb = qT + (size_t)bh * TT * HS;
  const f16* __restrict__ Kb = kT + (size_t)bh * TT * HS;
  const f16* __restrict__ Vb = vT + (size_t)bh * HS * TT;
  const int b = bh >> 4, h = bh & 15;

  __shared__ float O_m[2][64][33];   // [pl][lane][reg 0..31], +1 pad: 2-way max
  __shared__ float ML[2][64][2];

  #pragma unroll
  for (int half = 0; half < 2; ++half) {
    const int qt = half ? (63 - pair) : pair;
    const int q0 = qt * 32;
    const int qa = q0 + l31;
    f16x8 qf[4];
    #pragma unroll
    for (int j = 0; j < 4; ++j)
      qf[j] = *(const f16x8*)&Qb[(size_t)qa * HS + 16 * j + hi * 8];

    float m = -INFINITY, lsum = 0.f;
    f32x16 oA = {}, oB = {};

    const int lo = (qt + 1) >> 1;               // lower-half units
    const int kb0 = kh ? lo * 32 : 0;
    const int kb1 = kh ? qt * 32 : lo * 32;     // unmasked region end
    for (int kb = kb0; kb < kb1; kb += 32)
      step32<false>(kb, qa, l31, hi, Kb, Vb, qf, m, lsum, oA, oB);
    if (kh)
      step32<true>(qt * 32, qa, l31, hi, Kb, Vb, qf, m, lsum, oA, oB);

    lsum += __shfl_xor(lsum, 32);               // combine hi-half partials

    if (kh) {
      #pragma unroll
      for (int r = 0; r < 16; ++r) {
        O_m[pl][l][r]      = oA[r];
        O_m[pl][l][16 + r] = oB[r];
      }
      ML[pl][l][0] = m;
      ML[pl][l][1] = lsum;
    }
    __syncthreads();
    if (!kh) {
      float mB_ = ML[pl][l][0];
      float lB  = ML[pl][l][1];
      float mS = fmaxf(m, mB_);                  // mB_ always finite
      float cA = __builtin_amdgcn_exp2f(m - mS);
      float cB = __builtin_amdgcn_exp2f(mB_ - mS);
      float li = 1.0f / (lsum * cA + lB * cB);
      float sA = cA * li, sB = cB * li;
      f16* orow = aout + (size_t)(b * TT + qa) * CC + h * HS;
      #pragma unroll
      for (int rq = 0; rq < 4; ++rq) {
        f16x4 o4a, o4b;
        #pragma unroll
        for (int j = 0; j < 4; ++j) {
          int r = rq * 4 + j;
          o4a[j] = (f16)(oA[r] * sA + O_m[pl][l][r]      * sB);
          o4b[j] = (f16)(oB[r] * sA + O_m[pl][l][16 + r] * sB);
        }
        int dA = 8 * rq + 4 * hi;                // d = (r&3)+8*(r>>2)+4*hi
        *(f16x4*)&orow[dA]      = o4a;
        *(f16x4*)&orow[32 + dA] = o4b;
      }
    }
    __syncthreads();   // protect O_m/ML reuse by the second half
  }
}

// ---------------- launch ----------------
extern "C" void kernel_launch(void* const* d_in, const int* in_sizes, int n_in,
                              void* d_out, int out_size, void* d_ws, size_t ws_size,
                              hipStream_t stream) {
  const float* x      = (const float*)d_in[0];
  const float* w_kqv  = (const float*)d_in[1];
  const float* w_proj = (const float*)d_in[2];
  const float* b_proj = (const float*)d_in[3];
  float* out = (float*)d_out;

  char* ws = (char*)d_ws;
  f16* xb    = (f16*)(ws);                       // 16,777,216 B
  f16* wkqvT = (f16*)(ws + 16777216);            //  6,291,456
  f16* wpT   = (f16*)(ws + 23068672);            //  2,097,152
  f16* qT    = (f16*)(ws + 25165824);            // 16,777,216
  f16* kT    = (f16*)(ws + 41943040);            // 16,777,216
  f16* vT    = (f16*)(ws + 58720256);            // 16,777,216
  f16* aout  = (f16*)(ws + 75497472);            // 16,777,216  -> ~92.3 MB

  cvt_kernel<<<8192, 256, 0, stream>>>(x, xb, (MM * CC) / 4);
  transpose_cvt<<<dim3(3 * CC / 32, CC / 32), dim3(32, 8), 0, stream>>>(w_kqv, wkqvT, CC, 3 * CC);
  transpose_cvt<<<dim3(CC / 32, CC / 32), dim3(32, 8), 0, stream>>>(w_proj, wpT, CC, CC);

  gemm_bt<0><<<dim3(3 * CC / 128, MM / 128), 256, 0, stream>>>(xb, wkqvT, qT, kT, vT, nullptr, nullptr);

  attn_kernel<<<dim3(BB * HH, 16), 256, 0, stream>>>(qT, kT, vT, aout);

  gemm_bt<1><<<dim3(CC / 128, MM / 128), 256, 0, stream>>>(aout, wpT, nullptr, nullptr, nullptr, b_proj, out);
}